// Round 4
// baseline (42.139 us; speedup 1.0000x reference)
//
#include <hip/hip_runtime.h>

#define NSPLIT  4
#define NLAYERS 4
#define QPS     4
#define DIM     16
#define NCLS    5
#define BLK     256
#define RROWS   32

// LDS layout strides (words)
#define U_SS      520          // per-split stride for interleaved (re,im) U, padded
#define FE_STRIDE 17
#define H1_STRIDE 132          // 16B-aligned rows; banks (4r+4k)%32 tile perfectly for b128
#define H2_STRIDE 68

struct c32 { float x, y; };
__device__ __forceinline__ c32 cmul(c32 a, c32 b) { return c32{a.x*b.x - a.y*b.y, a.x*b.y + a.y*b.x}; }
__device__ __forceinline__ c32 cadd(c32 a, c32 b) { return c32{a.x + b.x, a.y + b.y}; }

// ---------------------------------------------------------------------------
// Single fused kernel. Per block (256 threads, 32 rows):
//   seg A: wave0 builds the 16 per-split 2x2 gates (parallel __sincosf);
//          waves1-3 stage W2 (32KB).
//   seg B: wave0 chains gates -> per-split 16x16 unitary U -> sU (LDS);
//          waves1-3 stage W1^T, biases, W3.  (overlapped)
//   Q:  quantum features (two real 16x16 matvecs per split, PauliZ signs)
//   M1: h1 = relu(feats @ W1 + b1)   -> sH1 [r][132]
//   M2: h2 = relu(h1 @ W2 + b2)      -> sH2 (h read as broadcast b128)
//   M3: out = h2 @ W3 + b3
// ---------------------------------------------------------------------------
__global__ __launch_bounds__(BLK) void qcnn_fused_kernel(
    const float* __restrict__ x,  const float* __restrict__ w,
    const float* __restrict__ W1, const float* __restrict__ b1,
    const float* __restrict__ W2, const float* __restrict__ b2,
    const float* __restrict__ W3, const float* __restrict__ b3,
    float* __restrict__ out, int B)
{
    __shared__ __align__(16) float sU[NSPLIT * U_SS];            // 8320 B
    __shared__ __align__(16) float sW1[128 * 16];                // 8192 B  [k1][f]
    __shared__ __align__(16) float sW2[128 * 64];                // 32768 B [k1][k2]
    __shared__ __align__(16) float sFe[RROWS * FE_STRIDE];       // 2176 B (aliases gate buf)
    __shared__ __align__(16) float sH1[RROWS * H1_STRIDE];       // 16896 B [r][k1]
    __shared__ __align__(16) float sH2[RROWS * H2_STRIDE];       // 8704 B  [r][k2]
    __shared__ float sb1[128], sb2[64], sW3b[64 * NCLS], sb3[NCLS];

    float* gUf = sFe;   // gate buffer [s*128 + g*8 + k], dead before sFe is written

    const int t = threadIdx.x;
    const int row0 = blockIdx.x * RROWS;

    // ---- segment A: gates (wave0) || stage W2 (waves1-3) ----
    if (t < 64) {
        const int s = t >> 4, g = t & 15;           // g = l*QPS + j
        const float* wp = w + (s * (NLAYERS * QPS) + g) * 3;
        const float hx = 0.5f * wp[0], hy = 0.5f * wp[1], hz = 0.5f * wp[2];
        float sx, cx, sy, cy, sz, cz;
        __sincosf(hx, &sx, &cx);
        __sincosf(hy, &sy, &cy);
        __sincosf(hz, &sz, &cz);
        const c32 X00{cx, 0.f}, X01{0.f, -sx}, X11{cx, 0.f};
        const c32 Y00{cy, 0.f}, Y01{-sy, 0.f}, Y10{sy, 0.f}, Y11{cy, 0.f};
        const c32 Z00{cz, -sz}, Z11{cz, sz};
        const c32 M00 = cadd(cmul(Y00, X00), cmul(Y01, X01));
        const c32 M01 = cadd(cmul(Y00, X01), cmul(Y01, X11));
        const c32 M10 = cadd(cmul(Y10, X00), cmul(Y11, X01));
        const c32 M11 = cadd(cmul(Y10, X01), cmul(Y11, X11));
        const c32 U00 = cmul(Z00, M00), U01 = cmul(Z00, M01);
        const c32 U10 = cmul(Z11, M10), U11 = cmul(Z11, M11);
        float* gp = gUf + s * 128 + g * 8;
        gp[0] = U00.x; gp[1] = U00.y; gp[2] = U01.x; gp[3] = U01.y;
        gp[4] = U10.x; gp[5] = U10.y; gp[6] = U11.x; gp[7] = U11.y;
    } else {
        for (int i = t - 64; i < 2048; i += 192)
            ((float4*)sW2)[i] = ((const float4*)W2)[i];
    }
    __syncthreads();

    // ---- segment B: chain gates (wave0) || stage the rest (waves1-3) ----
    if (t < 64) {
        const int s = t >> 4, col = t & 15;
        float str[DIM], sti[DIM];
        #pragma unroll
        for (int d = 0; d < DIM; ++d) { str[d] = (d == col) ? 1.0f : 0.0f; sti[d] = 0.0f; }

        #pragma unroll
        for (int l = 0; l < NLAYERS; ++l) {
            #pragma unroll
            for (int j = 0; j < QPS; ++j) {
                const float* gp = gUf + s * 128 + (l * QPS + j) * 8;
                const float4 u0 = *(const float4*)gp;        // U00.x U00.y U01.x U01.y
                const float4 u1 = *(const float4*)(gp + 4);  // U10.x U10.y U11.x U11.y
                const int p = 8 >> j;                        // wire j at bit (3-j)
                #pragma unroll
                for (int i0 = 0; i0 < DIM; ++i0) {
                    if (i0 & p) continue;
                    const int i1 = i0 | p;
                    const float ar = str[i0], ai = sti[i0];
                    const float br = str[i1], bi = sti[i1];
                    str[i0] = u0.x*ar - u0.y*ai + u0.z*br - u0.w*bi;
                    sti[i0] = u0.x*ai + u0.y*ar + u0.z*bi + u0.w*br;
                    str[i1] = u1.x*ar - u1.y*ai + u1.z*br - u1.w*bi;
                    sti[i1] = u1.x*ai + u1.y*ar + u1.z*bi + u1.w*br;
                }
            }
            // CNOT ring (register permutation, compile-time)
            #pragma unroll
            for (int j = 0; j < QPS; ++j) {
                const int pc = 8 >> j, pt = 8 >> ((j + 1) & 3);
                #pragma unroll
                for (int i = 0; i < DIM; ++i) {
                    if ((i & pc) && !(i & pt)) {
                        const int i1 = i | pt;
                        float tr = str[i]; str[i] = str[i1]; str[i1] = tr;
                        float ti = sti[i]; sti[i] = sti[i1]; sti[i1] = ti;
                    }
                }
            }
        }
        // write U interleaved (re,im) padded layout
        #pragma unroll
        for (int d = 0; d < DIM; ++d) {
            float2* up = (float2*)(sU + s * U_SS + d * 32 + 2 * col);
            *up = float2{str[d], sti[d]};
        }
    } else {
        const int tt = t - 64;
        for (int i = tt; i < 2048; i += 192) {
            const int k1 = i >> 4, f = i & 15;
            sW1[i] = W1[f * 128 + k1];                 // transpose: row k1 contiguous
        }
        for (int i = tt; i < 128;      i += 192) sb1[i] = b1[i];
        for (int i = tt; i < 64;       i += 192) sb2[i] = b2[i];
        for (int i = tt; i < 64 * NCLS; i += 192) sW3b[i] = W3[i];
        for (int i = tt; i < NCLS;     i += 192) sb3[i] = b3[i];
    }
    __syncthreads();

    // ---- phase Q: quantum features. thread = (row, split, d-half) ----
    {
        const int u = t >> 1, dh = t & 1;
        const int r = u >> 2, s = u & 3;
        int row = row0 + r; if (row >= B) row = B - 1;   // clamp (stores guarded later)

        float v[16];
        const float4* xp = (const float4*)(x + (size_t)row * 64 + s * 16);
        const float4 a0 = xp[0], a1 = xp[1], a2 = xp[2], a3 = xp[3];
        v[0]=a0.x;  v[1]=a0.y;  v[2]=a0.z;  v[3]=a0.w;
        v[4]=a1.x;  v[5]=a1.y;  v[6]=a1.z;  v[7]=a1.w;
        v[8]=a2.x;  v[9]=a2.y;  v[10]=a2.z; v[11]=a2.w;
        v[12]=a3.x; v[13]=a3.y; v[14]=a3.z; v[15]=a3.w;

        float n2 = 0.f;
        #pragma unroll
        for (int c = 0; c < 16; ++c) n2 += v[c] * v[c];
        const float inv2 = (n2 > 0.f) ? (1.0f / n2) : 1.0f;   // probs scale by 1/||v||^2

        float e0 = 0.f, e1 = 0.f, e2 = 0.f, e3 = 0.f;
        const float* ub = sU + s * U_SS + dh * (8 * 32);
        #pragma unroll
        for (int i = 0; i < 8; ++i) {
            const int d = dh * 8 + i;
            const float4* up = (const float4*)(ub + i * 32);
            float yr = 0.f, yi = 0.f;
            #pragma unroll
            for (int cp = 0; cp < 8; ++cp) {
                const float4 uu = up[cp];       // (re_c, im_c, re_{c+1}, im_{c+1})
                yr += uu.x * v[2*cp] + uu.z * v[2*cp + 1];
                yi += uu.y * v[2*cp] + uu.w * v[2*cp + 1];
            }
            const float p = (yr * yr + yi * yi) * inv2;
            e0 += (d & 8) ? -p : p;
            e1 += (d & 4) ? -p : p;
            e2 += (d & 2) ? -p : p;
            e3 += (d & 1) ? -p : p;
        }
        e0 += __shfl_xor(e0, 1);
        e1 += __shfl_xor(e1, 1);
        e2 += __shfl_xor(e2, 1);
        e3 += __shfl_xor(e3, 1);
        if (dh == 0) {
            float* fp = sFe + r * FE_STRIDE + s * 4;
            fp[0] = e0; fp[1] = e1; fp[2] = e2; fp[3] = e3;
        }
    }
    __syncthreads();

    // ---- phase M1: h1 = relu(feats @ W1 + b1), store [r][k1] (b128 writes) ----
    {
        const int r = t & 31, k1g = t >> 5;      // 8 groups of 16 k1
        float fv[16];
        #pragma unroll
        for (int f = 0; f < 16; ++f) fv[f] = sFe[r * FE_STRIDE + f];
        float res[16];
        #pragma unroll
        for (int kk = 0; kk < 16; ++kk) {
            const int k1 = k1g * 16 + kk;
            const float4* wp = (const float4*)(sW1 + k1 * 16);
            const float4 w0 = wp[0], w1 = wp[1], w2 = wp[2], w3 = wp[3];
            float a = sb1[k1]
                + w0.x*fv[0]  + w0.y*fv[1]  + w0.z*fv[2]  + w0.w*fv[3]
                + w1.x*fv[4]  + w1.y*fv[5]  + w1.z*fv[6]  + w1.w*fv[7]
                + w2.x*fv[8]  + w2.y*fv[9]  + w2.z*fv[10] + w2.w*fv[11]
                + w3.x*fv[12] + w3.y*fv[13] + w3.z*fv[14] + w3.w*fv[15];
            res[kk] = fmaxf(a, 0.f);
        }
        float4* dst = (float4*)(sH1 + r * H1_STRIDE + k1g * 16);
        #pragma unroll
        for (int q = 0; q < 4; ++q)
            dst[q] = float4{res[4*q], res[4*q+1], res[4*q+2], res[4*q+3]};
    }
    __syncthreads();

    // ---- phase M2: h2 = relu(h1 @ W2 + b2). thread = (row, 8 k2's) ----
    {
        const int oct = t & 7, r = t >> 3;       // r 0..31
        float acc[8];
        #pragma unroll
        for (int j = 0; j < 8; ++j) acc[j] = sb2[oct * 8 + j];
        const float4* h4  = (const float4*)(sH1 + r * H1_STRIDE);
        const float4* w2p = ((const float4*)sW2) + oct * 2;
        #pragma unroll 4
        for (int k4 = 0; k4 < 32; ++k4) {
            const float4 h = h4[k4];             // h1[r][4k4 .. 4k4+3], broadcast in 8-lane group
            {
                const float4 wa = w2p[(4*k4+0)*16], wb = w2p[(4*k4+0)*16 + 1];
                acc[0] += h.x*wa.x; acc[1] += h.x*wa.y; acc[2] += h.x*wa.z; acc[3] += h.x*wa.w;
                acc[4] += h.x*wb.x; acc[5] += h.x*wb.y; acc[6] += h.x*wb.z; acc[7] += h.x*wb.w;
            }
            {
                const float4 wa = w2p[(4*k4+1)*16], wb = w2p[(4*k4+1)*16 + 1];
                acc[0] += h.y*wa.x; acc[1] += h.y*wa.y; acc[2] += h.y*wa.z; acc[3] += h.y*wa.w;
                acc[4] += h.y*wb.x; acc[5] += h.y*wb.y; acc[6] += h.y*wb.z; acc[7] += h.y*wb.w;
            }
            {
                const float4 wa = w2p[(4*k4+2)*16], wb = w2p[(4*k4+2)*16 + 1];
                acc[0] += h.z*wa.x; acc[1] += h.z*wa.y; acc[2] += h.z*wa.z; acc[3] += h.z*wa.w;
                acc[4] += h.z*wb.x; acc[5] += h.z*wb.y; acc[6] += h.z*wb.z; acc[7] += h.z*wb.w;
            }
            {
                const float4 wa = w2p[(4*k4+3)*16], wb = w2p[(4*k4+3)*16 + 1];
                acc[0] += h.w*wa.x; acc[1] += h.w*wa.y; acc[2] += h.w*wa.z; acc[3] += h.w*wa.w;
                acc[4] += h.w*wb.x; acc[5] += h.w*wb.y; acc[6] += h.w*wb.z; acc[7] += h.w*wb.w;
            }
        }
        float4 o0, o1;
        o0.x = fmaxf(acc[0], 0.f); o0.y = fmaxf(acc[1], 0.f);
        o0.z = fmaxf(acc[2], 0.f); o0.w = fmaxf(acc[3], 0.f);
        o1.x = fmaxf(acc[4], 0.f); o1.y = fmaxf(acc[5], 0.f);
        o1.z = fmaxf(acc[6], 0.f); o1.w = fmaxf(acc[7], 0.f);
        float4* hp = (float4*)(sH2 + r * H2_STRIDE + oct * 8);
        hp[0] = o0; hp[1] = o1;
    }
    __syncthreads();

    // ---- phase M3: out = h2 @ W3 + b3. thread = (row, class), 160 active ----
    if (t < RROWS * NCLS) {
        const int r = t / NCLS, j = t - r * NCLS;
        float acc = sb3[j];
        const float4* hp = (const float4*)(sH2 + r * H2_STRIDE);
        #pragma unroll
        for (int q = 0; q < 16; ++q) {
            const float4 h = hp[q];
            acc += h.x * sW3b[(4*q + 0) * NCLS + j]
                 + h.y * sW3b[(4*q + 1) * NCLS + j]
                 + h.z * sW3b[(4*q + 2) * NCLS + j]
                 + h.w * sW3b[(4*q + 3) * NCLS + j];
        }
        const int row = row0 + r;
        if (row < B) out[(size_t)row * NCLS + j] = acc;
    }
}

extern "C" void kernel_launch(void* const* d_in, const int* in_sizes, int n_in,
                              void* d_out, int out_size, void* d_ws, size_t ws_size,
                              hipStream_t stream)
{
    (void)n_in; (void)out_size; (void)d_ws; (void)ws_size;
    const float* x  = (const float*)d_in[0];
    const float* sw = (const float*)d_in[1];
    const float* W1 = (const float*)d_in[2];
    const float* b1 = (const float*)d_in[3];
    const float* W2 = (const float*)d_in[4];
    const float* b2 = (const float*)d_in[5];
    const float* W3 = (const float*)d_in[6];
    const float* b3 = (const float*)d_in[7];
    float* out = (float*)d_out;

    const int B = in_sizes[0] / (NSPLIT * DIM);
    const int grid = (B + RROWS - 1) / RROWS;
    hipLaunchKernelGGL(qcnn_fused_kernel, dim3(grid), dim3(BLK), 0, stream,
                       x, sw, W1, b1, W2, b2, W3, b3, out, B);
}

// Round 5
// 39.764 us; speedup vs baseline: 1.0597x; 1.0597x over previous
//
#include <hip/hip_runtime.h>

#define NSPLIT  4
#define NLAYERS 4
#define QPS     4
#define DIM     16
#define NCLS    5
#define BLK     256
#define RROWS   32            // rows per block (8 per wave)

// LDS layout strides (words)
#define U_SS      520          // per-split stride for interleaved (re,im) U, padded (+8)
#define FE_STRIDE 20           // 16B-aligned rows, 20r mod 32 distinct for r=0..7
#define H1_STRIDE 132          // 16B-aligned; banks 4*rl spread perfectly

struct c32 { float x, y; };
__device__ __forceinline__ c32 cmul(c32 a, c32 b) { return c32{a.x*b.x - a.y*b.y, a.x*b.y + a.y*b.x}; }
__device__ __forceinline__ c32 cadd(c32 a, c32 b) { return c32{a.x + b.x, a.y + b.y}; }

// ---------------------------------------------------------------------------
// Kernel A (runs once, 1 block / 64 threads, ~3 us):
// phase 1: thread = (split, gate): build 2x2 gate via parallel __sincosf -> LDS
// phase 2: thread = (split, basis column): chain 16 gates through register
//          statevector -> per-split 16x16 unitary (columns) -> d_ws
// ---------------------------------------------------------------------------
__global__ void build_unitary_kernel(const float* __restrict__ w,
                                     float* __restrict__ Ur,
                                     float* __restrict__ Ui)
{
    __shared__ float gU[NSPLIT][NLAYERS * QPS][8];   // 2 KB

    const int t = threadIdx.x;            // 0..63

    {
        const int s = t >> 4, g = t & 15;           // g = l*QPS + j
        const float* wp = w + (s * (NLAYERS * QPS) + g) * 3;
        const float hx = 0.5f * wp[0], hy = 0.5f * wp[1], hz = 0.5f * wp[2];
        float sx, cx, sy, cy, sz, cz;
        __sincosf(hx, &sx, &cx);
        __sincosf(hy, &sy, &cy);
        __sincosf(hz, &sz, &cz);
        const c32 X00{cx, 0.f}, X01{0.f, -sx}, X11{cx, 0.f};
        const c32 Y00{cy, 0.f}, Y01{-sy, 0.f}, Y10{sy, 0.f}, Y11{cy, 0.f};
        const c32 Z00{cz, -sz}, Z11{cz, sz};
        const c32 M00 = cadd(cmul(Y00, X00), cmul(Y01, X01));
        const c32 M01 = cadd(cmul(Y00, X01), cmul(Y01, X11));
        const c32 M10 = cadd(cmul(Y10, X00), cmul(Y11, X01));
        const c32 M11 = cadd(cmul(Y10, X01), cmul(Y11, X11));
        const c32 U00 = cmul(Z00, M00), U01 = cmul(Z00, M01);
        const c32 U10 = cmul(Z11, M10), U11 = cmul(Z11, M11);
        float* gp = gU[s][g];
        gp[0] = U00.x; gp[1] = U00.y; gp[2] = U01.x; gp[3] = U01.y;
        gp[4] = U10.x; gp[5] = U10.y; gp[6] = U11.x; gp[7] = U11.y;
    }
    __syncthreads();

    const int s = t >> 4, col = t & 15;
    float str[DIM], sti[DIM];
    #pragma unroll
    for (int d = 0; d < DIM; ++d) { str[d] = (d == col) ? 1.0f : 0.0f; sti[d] = 0.0f; }

    #pragma unroll
    for (int l = 0; l < NLAYERS; ++l) {
        #pragma unroll
        for (int j = 0; j < QPS; ++j) {
            const float* gp = gU[s][l * QPS + j];
            const float4 u0 = *(const float4*)gp;        // U00.x U00.y U01.x U01.y
            const float4 u1 = *(const float4*)(gp + 4);  // U10.x U10.y U11.x U11.y
            const int p = 8 >> j;                        // wire j at bit (3-j)
            #pragma unroll
            for (int i0 = 0; i0 < DIM; ++i0) {
                if (i0 & p) continue;
                const int i1 = i0 | p;
                const float ar = str[i0], ai = sti[i0];
                const float br = str[i1], bi = sti[i1];
                str[i0] = u0.x*ar - u0.y*ai + u0.z*br - u0.w*bi;
                sti[i0] = u0.x*ai + u0.y*ar + u0.z*bi + u0.w*br;
                str[i1] = u1.x*ar - u1.y*ai + u1.z*br - u1.w*bi;
                sti[i1] = u1.x*ai + u1.y*ar + u1.z*bi + u1.w*br;
            }
        }
        #pragma unroll
        for (int j = 0; j < QPS; ++j) {
            const int pc = 8 >> j, pt = 8 >> ((j + 1) & 3);
            #pragma unroll
            for (int i = 0; i < DIM; ++i) {
                if ((i & pc) && !(i & pt)) {
                    const int i1 = i | pt;
                    float tr = str[i]; str[i] = str[i1]; str[i1] = tr;
                    float ti = sti[i]; sti[i] = sti[i1]; sti[i1] = ti;
                }
            }
        }
    }

    #pragma unroll
    for (int d = 0; d < DIM; ++d) {
        Ur[(s * DIM + d) * DIM + col] = str[d];
        Ui[(s * DIM + d) * DIM + col] = sti[d];
    }
}

// ---------------------------------------------------------------------------
// Kernel B: barrier-free wave-local. 256 threads = 4 waves; each wave owns
// 8 rows end-to-end (Q -> M1 -> M2 -> M3). One __syncthreads after staging;
// all later phase handoffs are within-wave (LDS slices are wave-private).
// ---------------------------------------------------------------------------
__global__ __launch_bounds__(BLK, 2) void qcnn_main_kernel(
    const float* __restrict__ x,
    const float* __restrict__ Ug,          // Ur[1024] then Ui[1024]
    const float* __restrict__ W1, const float* __restrict__ b1,
    const float* __restrict__ W2, const float* __restrict__ b2,
    const float* __restrict__ W3, const float* __restrict__ b3,
    float* __restrict__ out, int B)
{
    __shared__ __align__(16) float sU[NSPLIT * U_SS];            // 8320 B
    __shared__ __align__(16) float sW1[128 * 16 + 32];           // 8320 B  swizzled [k1][f]
    __shared__ __align__(16) float sW2[128 * 64];                // 32768 B [k1][k2]
    __shared__ __align__(16) float sFe[RROWS * FE_STRIDE];       // 2560 B  [r][f]
    __shared__ __align__(16) float sH1[RROWS * H1_STRIDE];       // 16896 B [r][k1]
    __shared__ float sb1[128], sb2[64], sW3b[64 * NCLS], sb3[8];

    const int t = threadIdx.x;
    const int w = t >> 6, lane = t & 63;
    const int row0 = blockIdx.x * RROWS;

    // ---- stage (all threads) ----
    {
        const float* Urg = Ug;
        const float* Uig = Ug + 1024;
        for (int i = t; i < 1024; i += BLK) {
            const int s = i >> 8, d = (i >> 4) & 15, c = i & 15;
            const int wd = s * U_SS + d * 32 + 2 * c;
            sU[wd] = Urg[i]; sU[wd + 1] = Uig[i];
        }
        for (int i = t; i < 2048; i += BLK) {
            const int k1 = i >> 4, f = i & 15;
            // swizzle: +((k1>>4)&7)*4 spreads M1's 8 g-groups over 8 bank groups
            sW1[k1 * 16 + ((k1 >> 4) & 7) * 4 + f] = W1[f * 128 + k1];
        }
        for (int i = t; i < 2048; i += BLK)
            ((float4*)sW2)[i] = ((const float4*)W2)[i];
        if (t < 128) sb1[t] = b1[t];
        if (t < 64)  sb2[t] = b2[t];
        for (int i = t; i < 64 * NCLS; i += BLK) sW3b[i] = W3[i];
        if (t < NCLS) sb3[t] = b3[t];
    }
    __syncthreads();   // the ONLY block-wide barrier

    // ==== phase Q: lane = (rl, s, dh) ; 8 rows x 4 splits x 2 halves ====
    {
        const int dh = lane & 1, s = (lane >> 1) & 3, rl = lane >> 3;
        int row = row0 + w * 8 + rl; if (row >= B) row = B - 1;

        float v[16];
        const float4* xp = (const float4*)(x + (size_t)row * 64 + s * 16);
        const float4 a0 = xp[0], a1 = xp[1], a2 = xp[2], a3 = xp[3];
        v[0]=a0.x;  v[1]=a0.y;  v[2]=a0.z;  v[3]=a0.w;
        v[4]=a1.x;  v[5]=a1.y;  v[6]=a1.z;  v[7]=a1.w;
        v[8]=a2.x;  v[9]=a2.y;  v[10]=a2.z; v[11]=a2.w;
        v[12]=a3.x; v[13]=a3.y; v[14]=a3.z; v[15]=a3.w;

        float n2 = 0.f;
        #pragma unroll
        for (int c = 0; c < 16; ++c) n2 += v[c] * v[c];
        const float inv2 = (n2 > 0.f) ? (1.0f / n2) : 1.0f;   // probs scale 1/||v||^2

        float e0 = 0.f, e1 = 0.f, e2 = 0.f, e3 = 0.f;
        const float* ub = sU + s * U_SS + dh * (8 * 32);
        #pragma unroll
        for (int i = 0; i < 8; ++i) {
            const int d = dh * 8 + i;
            const float4* up = (const float4*)(ub + i * 32);
            float yr = 0.f, yi = 0.f;
            #pragma unroll
            for (int cp = 0; cp < 8; ++cp) {
                const float4 uu = up[cp];       // (re_c, im_c, re_{c+1}, im_{c+1})
                yr += uu.x * v[2*cp] + uu.z * v[2*cp + 1];
                yi += uu.y * v[2*cp] + uu.w * v[2*cp + 1];
            }
            const float p = (yr * yr + yi * yi) * inv2;
            e0 += (d & 8) ? -p : p;
            e1 += (d & 4) ? -p : p;
            e2 += (d & 2) ? -p : p;
            e3 += (d & 1) ? -p : p;
        }
        e0 += __shfl_xor(e0, 1);
        e1 += __shfl_xor(e1, 1);
        e2 += __shfl_xor(e2, 1);
        e3 += __shfl_xor(e3, 1);
        if (dh == 0) {
            float4* fp = (float4*)(sFe + (w * 8 + rl) * FE_STRIDE + s * 4);
            *fp = float4{e0, e1, e2, e3};
        }
    }
    // (within-wave LDS RAW: compiler inserts lgkmcnt waits; no barrier needed)

    // ==== phase M1: lane = (rl, g); h1[g*16..g*16+15] for row rl ====
    {
        const int g = lane & 7, rl = lane >> 3;
        const float4* fp = (const float4*)(sFe + (w * 8 + rl) * FE_STRIDE);
        const float4 f0 = fp[0], f1 = fp[1], f2 = fp[2], f3 = fp[3];
        float res[16];
        #pragma unroll
        for (int kk = 0; kk < 16; ++kk) {
            const int k1 = g * 16 + kk;
            const float4* wp = (const float4*)(sW1 + k1 * 16 + g * 4);
            const float4 w0 = wp[0], w1 = wp[1], w2 = wp[2], w3 = wp[3];
            float a = sb1[k1]
                + w0.x*f0.x + w0.y*f0.y + w0.z*f0.z + w0.w*f0.w
                + w1.x*f1.x + w1.y*f1.y + w1.z*f1.z + w1.w*f1.w
                + w2.x*f2.x + w2.y*f2.y + w2.z*f2.z + w2.w*f2.w
                + w3.x*f3.x + w3.y*f3.y + w3.z*f3.z + w3.w*f3.w;
            res[kk] = fmaxf(a, 0.f);
        }
        float4* dst = (float4*)(sH1 + (w * 8 + rl) * H1_STRIDE + g * 16);
        #pragma unroll
        for (int q = 0; q < 4; ++q)
            dst[q] = float4{res[4*q], res[4*q+1], res[4*q+2], res[4*q+3]};
    }

    // ==== phase M2: lane = (rl, oct); 8 k2's per lane ====
    float acc[8];
    {
        const int oct = lane & 7, rl = lane >> 3;
        #pragma unroll
        for (int j = 0; j < 8; ++j) acc[j] = sb2[oct * 8 + j];
        const float4* h4  = (const float4*)(sH1 + (w * 8 + rl) * H1_STRIDE);
        const float4* w2p = ((const float4*)sW2) + oct * 2;
        #pragma unroll 4
        for (int k4 = 0; k4 < 32; ++k4) {
            const float4 h = h4[k4];
            {
                const float4 wa = w2p[(4*k4+0)*16], wb = w2p[(4*k4+0)*16 + 1];
                acc[0] += h.x*wa.x; acc[1] += h.x*wa.y; acc[2] += h.x*wa.z; acc[3] += h.x*wa.w;
                acc[4] += h.x*wb.x; acc[5] += h.x*wb.y; acc[6] += h.x*wb.z; acc[7] += h.x*wb.w;
            }
            {
                const float4 wa = w2p[(4*k4+1)*16], wb = w2p[(4*k4+1)*16 + 1];
                acc[0] += h.y*wa.x; acc[1] += h.y*wa.y; acc[2] += h.y*wa.z; acc[3] += h.y*wa.w;
                acc[4] += h.y*wb.x; acc[5] += h.y*wb.y; acc[6] += h.y*wb.z; acc[7] += h.y*wb.w;
            }
            {
                const float4 wa = w2p[(4*k4+2)*16], wb = w2p[(4*k4+2)*16 + 1];
                acc[0] += h.z*wa.x; acc[1] += h.z*wa.y; acc[2] += h.z*wa.z; acc[3] += h.z*wa.w;
                acc[4] += h.z*wb.x; acc[5] += h.z*wb.y; acc[6] += h.z*wb.z; acc[7] += h.z*wb.w;
            }
            {
                const float4 wa = w2p[(4*k4+3)*16], wb = w2p[(4*k4+3)*16 + 1];
                acc[0] += h.w*wa.x; acc[1] += h.w*wa.y; acc[2] += h.w*wa.z; acc[3] += h.w*wa.w;
                acc[4] += h.w*wb.x; acc[5] += h.w*wb.y; acc[6] += h.w*wb.z; acc[7] += h.w*wb.w;
            }
        }
    }

    // ==== phase M3: per-lane partial dot, shfl_xor reduce over oct ====
    {
        const int oct = lane & 7, rl = lane >> 3;
        float o0 = 0.f, o1 = 0.f, o2 = 0.f, o3 = 0.f, o4 = 0.f;
        #pragma unroll
        for (int i = 0; i < 8; ++i) {
            const float h = fmaxf(acc[i], 0.f);           // relu(h2)
            const float* wr = sW3b + (oct * 8 + i) * NCLS;
            o0 += h * wr[0]; o1 += h * wr[1]; o2 += h * wr[2];
            o3 += h * wr[3]; o4 += h * wr[4];
        }
        #pragma unroll
        for (int m = 1; m <= 4; m <<= 1) {
            o0 += __shfl_xor(o0, m);
            o1 += __shfl_xor(o1, m);
            o2 += __shfl_xor(o2, m);
            o3 += __shfl_xor(o3, m);
            o4 += __shfl_xor(o4, m);
        }
        const int row = row0 + w * 8 + rl;
        if (oct < NCLS && row < B) {
            const float val = (oct == 0) ? o0 : (oct == 1) ? o1 :
                              (oct == 2) ? o2 : (oct == 3) ? o3 : o4;
            out[(size_t)row * NCLS + oct] = val + sb3[oct];
        }
    }
}

extern "C" void kernel_launch(void* const* d_in, const int* in_sizes, int n_in,
                              void* d_out, int out_size, void* d_ws, size_t ws_size,
                              hipStream_t stream)
{
    (void)n_in; (void)out_size; (void)ws_size;
    const float* x  = (const float*)d_in[0];
    const float* sw = (const float*)d_in[1];
    const float* W1 = (const float*)d_in[2];
    const float* b1 = (const float*)d_in[3];
    const float* W2 = (const float*)d_in[4];
    const float* b2 = (const float*)d_in[5];
    const float* W3 = (const float*)d_in[6];
    const float* b3 = (const float*)d_in[7];
    float* out = (float*)d_out;

    float* Ur = (float*)d_ws;                  // 1024 floats
    float* Ui = Ur + 1024;                     // 1024 floats

    const int B = in_sizes[0] / (NSPLIT * DIM);

    hipLaunchKernelGGL(build_unitary_kernel, dim3(1), dim3(64), 0, stream, sw, Ur, Ui);

    const int grid = (B + RROWS - 1) / RROWS;
    hipLaunchKernelGGL(qcnn_main_kernel, dim3(grid), dim3(BLK), 0, stream,
                       x, (const float*)d_ws, W1, b1, W2, b2, W3, b3, out, B);
}